// Round 3
// baseline (67.752 us; speedup 1.0000x reference)
//
#include <hip/hip_runtime.h>

namespace {

constexpr int S_LEN = 2048;
constexpr int H_N   = 8;
constexpr int D_DIM = 64;
constexpr int N_DIM = 32;
constexpr float NLOG2E = -1.4426950408889634f;

// Work split: lane = nh*32 + dlow ; each thread owns 16 of the 32 n-states.
// Wave unit W = (chunk, bh, dbase): dbase = (W&1)*32, bh = (W>>1)&15, chunk = W>>5.
// ws layout:
//   agg : [chunk][slot 0..63][ch 0..1023]  slot n = aProd[n], 32+n = bAgg[n]
//   pref: [chunk][n 0..31 ][ch 0..1023]    prefix state entering chunk
// agg chunk stride = 65536 floats; pref chunk stride = 32768 floats.

template<int L>
__global__ __launch_bounds__(256, 4) void ssm_chunk_agg(
    const float* __restrict__ dtp, const float* __restrict__ up,
    const float* __restrict__ Ap,  const float* __restrict__ Bp,
    float* __restrict__ agg)
{
    const int w    = threadIdx.x >> 6;
    const int lane = threadIdx.x & 63;
    const int W    = blockIdx.x * 4 + w;
    const int dbase = __builtin_amdgcn_readfirstlane((W & 1) * 32);
    const int bh    = __builtin_amdgcn_readfirstlane((W >> 1) & 15);
    const int chunk = __builtin_amdgcn_readfirstlane(W >> 5);
    const int b = bh >> 3, hh = bh & 7;
    const int dlow = lane & 31, nh = lane >> 5;
    const int d  = dbase + dlow;
    const int n0 = nh * 16;
    const int ch = bh * 64 + d;

    const float* Arow = Ap + (hh * D_DIM + d) * N_DIM + n0;
    float Aneg[16];
#pragma unroll
    for (int j = 0; j < 16; ++j) Aneg[j] = NLOG2E * Arow[j];

    float aP[16], bA[16];
#pragma unroll
    for (int j = 0; j < 16; ++j) { aP[j] = 1.0f; bA[j] = 0.0f; }

    const int base_ud = b * (S_LEN * H_N * D_DIM) + hh * D_DIM + d;
    const int base_bc = b * (S_LEN * H_N * N_DIM) + hh * N_DIM + n0;
    const int s0 = chunk * L;

#pragma unroll 4
    for (int t = 0; t < L; ++t) {
        const int s = s0 + t;
        const float dtv = dtp[base_ud + s * (H_N * D_DIM)];
        const float uv  = up [base_ud + s * (H_N * D_DIM)];
        const float kk  = dtv * uv;
        const float4* B4 = reinterpret_cast<const float4*>(Bp + base_bc + s * (H_N * N_DIM));
        float Br[16];
#pragma unroll
        for (int j = 0; j < 4; ++j) {
            float4 v = B4[j];
            Br[4*j+0] = v.x; Br[4*j+1] = v.y; Br[4*j+2] = v.z; Br[4*j+3] = v.w;
        }
#pragma unroll
        for (int j = 0; j < 16; ++j) {
            const float e = __builtin_amdgcn_exp2f(dtv * Aneg[j]);
            aP[j] = aP[j] * e;
            bA[j] = fmaf(e, bA[j], kk * Br[j]);
        }
    }

    const int aggbase = chunk * (64 * 1024) + ch;
#pragma unroll
    for (int j = 0; j < 16; ++j) {
        agg[aggbase + (n0 + j) * 1024]        = aP[j];
        agg[aggbase + (32 + n0 + j) * 1024]   = bA[j];
    }
}

__global__ __launch_bounds__(256) void ssm_chunk_scan(
    const float* __restrict__ agg, float* __restrict__ pref, int NC)
{
    const int T  = blockIdx.x * 256 + threadIdx.x;   // 32768 threads = (n, ch)
    const int ch = T & 1023;
    const int n  = T >> 10;
    const float* ap = agg + n * 1024 + ch;
    const float* bp = agg + (32 + n) * 1024 + ch;
    float*       pp = pref + n * 1024 + ch;

    float p = 0.0f;
    for (int k = 0; k < NC; k += 4) {
        const float a0 = ap[(size_t)(k + 0) * 65536], b0 = bp[(size_t)(k + 0) * 65536];
        const float a1 = ap[(size_t)(k + 1) * 65536], b1 = bp[(size_t)(k + 1) * 65536];
        const float a2 = ap[(size_t)(k + 2) * 65536], b2 = bp[(size_t)(k + 2) * 65536];
        const float a3 = ap[(size_t)(k + 3) * 65536], b3 = bp[(size_t)(k + 3) * 65536];
        pp[(size_t)(k + 0) * 32768] = p; p = fmaf(a0, p, b0);
        pp[(size_t)(k + 1) * 32768] = p; p = fmaf(a1, p, b1);
        pp[(size_t)(k + 2) * 32768] = p; p = fmaf(a2, p, b2);
        pp[(size_t)(k + 3) * 32768] = p; p = fmaf(a3, p, b3);
    }
}

template<int L>
__global__ __launch_bounds__(256, 3) void ssm_chunk_out(
    const float* __restrict__ dtp, const float* __restrict__ up,
    const float* __restrict__ Ap,  const float* __restrict__ Bp,
    const float* __restrict__ Cp,  const float* __restrict__ Dp,
    const float* __restrict__ pref, float* __restrict__ outp)
{
    const int w    = threadIdx.x >> 6;
    const int lane = threadIdx.x & 63;
    const int W    = blockIdx.x * 4 + w;
    const int dbase = __builtin_amdgcn_readfirstlane((W & 1) * 32);
    const int bh    = __builtin_amdgcn_readfirstlane((W >> 1) & 15);
    const int chunk = __builtin_amdgcn_readfirstlane(W >> 5);
    const int b = bh >> 3, hh = bh & 7;
    const int dlow = lane & 31, nh = lane >> 5;
    const int d  = dbase + dlow;
    const int n0 = nh * 16;
    const int ch = bh * 64 + d;

    const float* Arow = Ap + (hh * D_DIM + d) * N_DIM + n0;
    float Aneg[16];
#pragma unroll
    for (int j = 0; j < 16; ++j) Aneg[j] = NLOG2E * Arow[j];

    float h[16];
    {
        const int pbase = chunk * (32 * 1024) + ch;
#pragma unroll
        for (int j = 0; j < 16; ++j) h[j] = pref[pbase + (n0 + j) * 1024];
    }

    const float Dv = Dp[hh];
    const int base_ud = b * (S_LEN * H_N * D_DIM) + hh * D_DIM + d;
    const int base_bc = b * (S_LEN * H_N * N_DIM) + hh * N_DIM + n0;
    const int s0 = chunk * L;

#pragma unroll 4
    for (int t = 0; t < L; ++t) {
        const int s = s0 + t;
        const float dtv = dtp[base_ud + s * (H_N * D_DIM)];
        const float uv  = up [base_ud + s * (H_N * D_DIM)];
        const float kk  = dtv * uv;
        const float4* B4 = reinterpret_cast<const float4*>(Bp + base_bc + s * (H_N * N_DIM));
        const float4* C4 = reinterpret_cast<const float4*>(Cp + base_bc + s * (H_N * N_DIM));
        float Br[16], Cr[16];
#pragma unroll
        for (int j = 0; j < 4; ++j) {
            float4 v = B4[j];
            Br[4*j+0] = v.x; Br[4*j+1] = v.y; Br[4*j+2] = v.z; Br[4*j+3] = v.w;
            float4 c = C4[j];
            Cr[4*j+0] = c.x; Cr[4*j+1] = c.y; Cr[4*j+2] = c.z; Cr[4*j+3] = c.w;
        }
        float y0 = 0.0f, y1 = 0.0f, y2 = 0.0f, y3 = 0.0f;
#pragma unroll
        for (int j = 0; j < 16; ++j) {
            const float e = __builtin_amdgcn_exp2f(dtv * Aneg[j]);
            h[j] = fmaf(e, h[j], kk * Br[j]);
            if ((j & 3) == 0)      y0 = fmaf(h[j], Cr[j], y0);
            else if ((j & 3) == 1) y1 = fmaf(h[j], Cr[j], y1);
            else if ((j & 3) == 2) y2 = fmaf(h[j], Cr[j], y2);
            else                   y3 = fmaf(h[j], Cr[j], y3);
        }
        float y = (y0 + y1) + (y2 + y3);
        y += __shfl_xor(y, 32);
        if (nh == 0) outp[base_ud + s * (H_N * D_DIM)] = fmaf(Dv, uv, y);
    }
}

} // namespace

extern "C" void kernel_launch(void* const* d_in, const int* in_sizes, int n_in,
                              void* d_out, int out_size, void* d_ws, size_t ws_size,
                              hipStream_t stream)
{
    const float* u  = (const float*)d_in[0];
    const float* dt = (const float*)d_in[1];
    const float* A  = (const float*)d_in[2];
    const float* B  = (const float*)d_in[3];
    const float* C  = (const float*)d_in[4];
    const float* D  = (const float*)d_in[5];
    float* out = (float*)d_out;

    // pick largest NC whose agg+pref fit: NC * (64+32) * 1024 * 4 bytes
    int NC = 128;
    while (NC > 8 && (size_t)NC * 96 * 1024 * sizeof(float) > ws_size) NC >>= 1;
    const int L = S_LEN / NC;

    float* agg  = (float*)d_ws;
    float* pref = agg + (size_t)NC * 64 * 1024;

    dim3 blk(256);
    const int nblk = NC * 16 * 2 / 4;   // waves = NC*16bh*2dbase, 4 waves/block

    switch (L) {
    case 16:
        ssm_chunk_agg<16><<<dim3(nblk), blk, 0, stream>>>(dt, u, A, B, agg);
        ssm_chunk_scan  <<<dim3(128),   blk, 0, stream>>>(agg, pref, NC);
        ssm_chunk_out<16><<<dim3(nblk), blk, 0, stream>>>(dt, u, A, B, C, D, pref, out);
        break;
    case 32:
        ssm_chunk_agg<32><<<dim3(nblk), blk, 0, stream>>>(dt, u, A, B, agg);
        ssm_chunk_scan  <<<dim3(128),   blk, 0, stream>>>(agg, pref, NC);
        ssm_chunk_out<32><<<dim3(nblk), blk, 0, stream>>>(dt, u, A, B, C, D, pref, out);
        break;
    default:
        ssm_chunk_agg<64><<<dim3(nblk), blk, 0, stream>>>(dt, u, A, B, agg);
        ssm_chunk_scan  <<<dim3(128),   blk, 0, stream>>>(agg, pref, NC);
        ssm_chunk_out<64><<<dim3(nblk), blk, 0, stream>>>(dt, u, A, B, C, D, pref, out);
        break;
    }
}